// Round 6
// baseline (390.065 us; speedup 1.0000x reference)
//
#include <hip/hip_runtime.h>
#include <hip/hip_bf16.h>

// ---------------- helpers ----------------
typedef __attribute__((ext_vector_type(8))) short short8;
typedef __attribute__((ext_vector_type(4))) float floatx4;

__device__ __forceinline__ unsigned short f2bfu(float f) {
    unsigned u = __float_as_uint(f);
    unsigned rounding = 0x7fffu + ((u >> 16) & 1u);
    return (unsigned short)((u + rounding) >> 16);
}
__device__ __forceinline__ float bfu2f(unsigned short u) {
    return __uint_as_float(((unsigned)u) << 16);
}

// async global->LDS, 16B per lane; LDS dest = wave-uniform base + lane*16
__device__ __forceinline__ void async_ld16(const void* g, void* l) {
    __builtin_amdgcn_global_load_lds(
        (const __attribute__((address_space(1))) void*)g,
        (__attribute__((address_space(3))) void*)l, 16, 0, 0);
}

#define B_  8
#define N_  2048
#define C_  512
#define NC_ 16   // clusters
#define SL_ 8    // cluster_reduce row slices

// ---------------- convert kernels ----------------
__global__ __launch_bounds__(256) void cvt_x(const float4* __restrict__ x,
                                             unsigned short* __restrict__ xbf) {
    size_t i = (size_t)blockIdx.x * 256 + threadIdx.x;   // 4 floats per thread
    float4 f = x[i];
    unsigned short u0 = f2bfu(f.x), u1 = f2bfu(f.y), u2 = f2bfu(f.z), u3 = f2bfu(f.w);
    uint2 p;
    p.x = (unsigned)u0 | ((unsigned)u1 << 16);
    p.y = (unsigned)u2 | ((unsigned)u3 << 16);
    *(uint2*)(xbf + 4 * i) = p;
}

// WqkT[n][k], n in [0,1024), k in [0,512): = Wqk[k][n]   (v is eliminated algebraically)
__global__ __launch_bounds__(256) void cvt_wqk(const float* __restrict__ Wqk,
                                               unsigned short* __restrict__ WT) {
    int id = blockIdx.x * 256 + threadIdx.x;   // 1024*512 total
    int n = id >> 9, k = id & 511;
    WT[id] = f2bfu(Wqk[(size_t)k * 1024 + n]);
}

// ---------------- stable counting sort per batch ----------------
__global__ __launch_bounds__(256) void sort_kernel(const int* __restrict__ idx_cluster,
                                                   int* __restrict__ shuf,
                                                   int* __restrict__ restore,
                                                   int* __restrict__ svals,
                                                   int* __restrict__ dbl,
                                                   int* __restrict__ cstart) {
    int b = blockIdx.x, t = threadIdx.x;
    __shared__ int vals[N_];
    __shared__ int seghist[256 * 17];   // stride 17 to spread banks
    __shared__ int cbase[NC_], ctot[NC_];
    __shared__ int shufs[N_];
    const int* src = idx_cluster + (size_t)b * N_;
    for (int j = t; j < N_; j += 256) vals[j] = src[j];
    for (int c = 0; c < NC_; ++c) seghist[t * 17 + c] = 0;
    __syncthreads();
    // count: thread t owns positions t*8 .. t*8+7 (contiguous -> stable)
    for (int i = 0; i < 8; ++i) {
        int c = vals[t * 8 + i];
        seghist[t * 17 + c]++;
    }
    __syncthreads();
    if (t < NC_) {   // exclusive scan over segments for cluster t
        int run = 0;
        for (int s = 0; s < 256; ++s) {
            int x = seghist[s * 17 + t];
            seghist[s * 17 + t] = run;
            run += x;
        }
        ctot[t] = run;
    }
    __syncthreads();
    if (t == 0) {
        int run = 0;
        for (int c = 0; c < NC_; ++c) {
            cbase[c] = run;
            cstart[b * 17 + c] = run;
            run += ctot[c];
        }
        cstart[b * 17 + NC_] = run;   // == N_
    }
    __syncthreads();
    for (int i = 0; i < 8; ++i) {
        int p = t * 8 + i;
        int c = vals[p];
        int pos = cbase[c] + seghist[t * 17 + c];
        seghist[t * 17 + c]++;
        shufs[pos] = p;
    }
    __syncthreads();
    for (int j = t; j < N_; j += 256) {
        int sj = shufs[j];
        shuf[(size_t)b * N_ + j] = sj;
        svals[(size_t)b * N_ + j] = vals[sj];
        restore[(size_t)b * N_ + sj] = j;
        dbl[(size_t)b * N_ + j] = shufs[sj];
    }
}

// ---------------- bf16 MFMA GEMM, A (MxK) row-major, Bt (NxK) row-major ----------------
// EXACT R0 core, NO block remap (A/B isolated the XCD swizzle as a ~+40us regression
// in this L3-resident regime -- every swizzled round R3/R4/R5 carried it).
// Single-buffer 128x64 tiles (32 KiB LDS, 3 blocks/CU), 2 __syncthreads per K-step,
// global_load_lds width=16 staging, source-side XOR swizzle (chunk ^= row&7).
// MODE 0: qk   (N=1024) -> split bf16 q/k
// MODE 1: attn (per-batch 2048x2048) -> f32 * SCALE
template <int MODE>
__global__ __launch_bounds__(256) void gemm_bt(const unsigned short* __restrict__ A,
                                               const unsigned short* __restrict__ Bt,
                                               float* __restrict__ outF,
                                               unsigned short* __restrict__ outQ,
                                               unsigned short* __restrict__ outK) {
    constexpr int K = 512;
    int t = threadIdx.x;
    int lane = t & 63, wave = t >> 6;
    int wm = (wave & 1) * 64, wn = (wave >> 1) * 64;
    int m0 = blockIdx.y * 128, n0 = blockIdx.x * 128;
    if (MODE == 1) {
        size_t b = blockIdx.z;
        A += b * (size_t)N_ * 512;
        Bt += b * (size_t)N_ * 512;
        outF += b * (size_t)N_ * N_;
    }
    __shared__ __align__(16) unsigned short As[128 * 64];
    __shared__ __align__(16) unsigned short Bs[128 * 64];
    floatx4 acc[4][4] = {};
    int l15 = lane & 15, q4 = lane >> 4;
    // staging: lane covers row (lane>>3) within its 8-row group, chunk (lane&7)
    int srow = lane >> 3, schk = lane & 7;
    int sgc = schk ^ srow;            // source chunk after XOR swizzle (row&7 == srow)
    int xr = l15 & 7;                 // fragment-read XOR (row&7 == l15&7 for all mi/ni)

    for (int k0 = 0; k0 < K; k0 += 64) {
        __syncthreads();   // previous-iter LDS reads done before overwrite
#pragma unroll
        for (int i = 0; i < 4; ++i) {
            int cid = i * 4 + wave;                 // 1KB group id (16 groups of 8 rows)
            int row = cid * 8 + srow;
            async_ld16(A + (size_t)(m0 + row) * 512 + k0 + sgc * 8, (char*)As + cid * 1024);
            async_ld16(Bt + (size_t)(n0 + row) * 512 + k0 + sgc * 8, (char*)Bs + cid * 1024);
        }
        __syncthreads();   // drains vmcnt (async LDS writes visible)
#pragma unroll
        for (int kk = 0; kk < 2; ++kk) {
            int csw = (((kk * 4 + q4) ^ xr) * 8);   // swizzled chunk offset (elements)
            short8 af[4], bfr[4];
#pragma unroll
            for (int mi = 0; mi < 4; ++mi)
                af[mi] = *(const short8*)(&As[(wm + mi * 16 + l15) * 64 + csw]);
#pragma unroll
            for (int ni = 0; ni < 4; ++ni)
                bfr[ni] = *(const short8*)(&Bs[(wn + ni * 16 + l15) * 64 + csw]);
#pragma unroll
            for (int mi = 0; mi < 4; ++mi)
#pragma unroll
                for (int ni = 0; ni < 4; ++ni)
                    acc[mi][ni] = __builtin_amdgcn_mfma_f32_16x16x32_bf16(af[mi], bfr[ni], acc[mi][ni], 0, 0, 0);
        }
    }
    // epilogue: D[row=q4*4+r][col=l15] per 16x16 tile
#pragma unroll
    for (int mi = 0; mi < 4; ++mi) {
#pragma unroll
        for (int ni = 0; ni < 4; ++ni) {
#pragma unroll
            for (int r = 0; r < 4; ++r) {
                int row = m0 + wm + mi * 16 + q4 * 4 + r;
                int col = n0 + wn + ni * 16 + l15;
                float v = acc[mi][ni][r];
                if (MODE == 0) {
                    unsigned short u = f2bfu(v);
                    if (col < 512) outQ[(size_t)row * 512 + col] = u;
                    else           outK[(size_t)row * 512 + col - 512] = u;
                } else {
                    outF[(size_t)row * N_ + col] = v * 0.125f;
                }
            }
        }
    }
}

// ---------------- sliced per-(batch,cluster) softmax-collapse reduction ----------------
// e_j = exp(attn[b, dbl[j], j]);  slice sl handles rows i in [n*sl/8, n*(sl+1)/8)
// v is eliminated: xepart[b][sl][c][d] = sum_{i in slice} e_i * x_bf[b,shuf[i],d]
// (since sum e_i * (x@Wv)[shuf_i] == (sum e_i * x[shuf_i]) @ Wv).
// Spart[b][sl][c] = sum_{i in slice} e_i
__global__ __launch_bounds__(256) void cluster_reduce2(const float* __restrict__ attn,
                                                       const int* __restrict__ shuf,
                                                       const int* __restrict__ dbl,
                                                       const int* __restrict__ cstart,
                                                       const unsigned short* __restrict__ xbf,
                                                       float* __restrict__ xepart,
                                                       float* __restrict__ Spart) {
    int c = blockIdx.x, b = blockIdx.y, sl = blockIdx.z, t = threadIdx.x;
    int start = cstart[b * 17 + c], end = cstart[b * 17 + c + 1];
    int n = end - start;
    int i0 = (n * sl) / SL_, i1 = (n * (sl + 1)) / SL_;
    int cnt = i1 - i0;                 // <= ceil(2048/8) = 256
    __shared__ float e_lds[256];
    __shared__ int row_lds[256];
    if (t < cnt) {
        int j = start + i0 + t;
        int dj = dbl[(size_t)b * N_ + j];
        float e = expf(attn[(size_t)b * N_ * N_ + (size_t)dj * N_ + j]);
        e_lds[t] = e;
        row_lds[t] = shuf[(size_t)b * N_ + j];
    }
    __syncthreads();
    if (t == 0) {
        float s = 0.f;
        for (int i = 0; i < cnt; ++i) s += e_lds[i];
        Spart[(b * SL_ + sl) * NC_ + c] = s;
    }
    float a0 = 0.f, a1 = 0.f;
    for (int i = 0; i < cnt; ++i) {
        float e = e_lds[i];
        unsigned u = *(const unsigned*)(xbf + ((size_t)b * N_ + row_lds[i]) * 512 + 2 * t);
        a0 += e * bfu2f((unsigned short)u);
        a1 += e * bfu2f((unsigned short)(u >> 16));
    }
    float2 o; o.x = a0; o.y = a1;
    *(float2*)(xepart + (((size_t)(b * SL_ + sl) * NC_ + c) * 512 + 2 * t)) = o;
}

// ---------------- combine slice partials -> xe[b][c][512] (f32) + Stot ----------------
__global__ __launch_bounds__(256) void combine_xe(const float* __restrict__ xepart,
                                                  const float* __restrict__ Spart,
                                                  float* __restrict__ xe,
                                                  float* __restrict__ Stot) {
    int c = blockIdx.x, b = blockIdx.y, t = threadIdx.x;
    float a0 = 0.f, a1 = 0.f;
    for (int sl = 0; sl < SL_; ++sl) {
        float2 o = *(const float2*)(xepart + (((size_t)(b * SL_ + sl) * NC_ + c) * 512 + 2 * t));
        a0 += o.x; a1 += o.y;
    }
    float2 r; r.x = a0; r.y = a1;
    *(float2*)(xe + ((size_t)b * NC_ + c) * 512 + 2 * t) = r;
    if (t == 0) {
        float S = 0.f;
        for (int sl = 0; sl < SL_; ++sl) S += Spart[(b * SL_ + sl) * NC_ + c];
        Stot[b * NC_ + c] = S;
    }
}

// ---------------- O = (xe @ Wv) / S, stored transposed Ot[b][d][c] ----------------
// 128 blocks; Wv (1 MB f32) is L2/L3-resident across blocks.
__global__ __launch_bounds__(256) void ovw_kernel(const float* __restrict__ xe,
                                                  const float* __restrict__ Stot,
                                                  const float* __restrict__ Wv,
                                                  float* __restrict__ Ot) {
    int c = blockIdx.x, b = blockIdx.y, t = threadIdx.x;
    __shared__ float xl[512];
    for (int i = t; i < 512; i += 256) xl[i] = xe[((size_t)b * NC_ + c) * 512 + i];
    __syncthreads();
    float S = Stot[b * NC_ + c];
    float inv = S > 0.f ? 1.f / S : 0.f;
    float a0 = 0.f, a1 = 0.f;
    for (int k = 0; k < 512; ++k) {
        float xv = xl[k];                                  // LDS broadcast
        float2 w = *(const float2*)(Wv + (size_t)k * 512 + 2 * t);
        a0 += xv * w.x; a1 += xv * w.y;
    }
    Ot[((size_t)b * 512 + 2 * t) * NC_ + c] = a0 * inv;
    Ot[((size_t)b * 512 + 2 * t + 1) * NC_ + c] = a1 * inv;
}

// ---------------- grouped projection weights (parallel, range-based) ----------------
// svals is sorted: cluster c occupies global rows [cstart[b][c], cstart[b][c+1]).
// Within group g (rows [512g, 512(g+1))): Wg[b][g][c][m] = sum_{cd=lo}^{hi-1} Wproj[cd][m].
__global__ __launch_bounds__(256) void build_wg(const float* __restrict__ Wproj,
                                                const int* __restrict__ cstart,
                                                unsigned int* __restrict__ Wg) {
    int c = blockIdx.x;          // cluster
    int bg = blockIdx.y;         // b*4+g
    int b = bg >> 2, g = bg & 3;
    int t = threadIdx.x;
    int lo = cstart[b * 17 + c] - g * 512;
    int hi = cstart[b * 17 + c + 1] - g * 512;
    lo = lo < 0 ? 0 : lo;
    hi = hi > 512 ? 512 : hi;
    float a0 = 0.f, a1 = 0.f;
    for (int cd = lo; cd < hi; ++cd) {
        float2 w = *(const float2*)(Wproj + (size_t)cd * 512 + 2 * t);
        a0 += w.x; a1 += w.y;
    }
    Wg[(size_t)bg * NC_ * 256 + c * 256 + t] =
        (unsigned)f2bfu(a0) | ((unsigned)f2bfu(a1) << 16);   // empty range -> 0
}

// ---------------- final projection: x_out[b,n,m] = sum_c Ot[b,rq,c]*Wg[b,g,c,m] + bias[m] ----
// r = restore[b,n]; rq = r>>2; g = r&3.  K=16 contraction, O stays f32.
__global__ __launch_bounds__(256) void xout_kernel(const float* __restrict__ Ot,
                                                   const unsigned int* __restrict__ Wg,
                                                   const int* __restrict__ restore,
                                                   const float* __restrict__ bias,
                                                   float* __restrict__ xout) {
    int nb = blockIdx.x, b = blockIdx.y, t = threadIdx.x;
    int n0 = nb * 64;
    __shared__ int r_lds[64];
    if (t < 64) r_lds[t] = restore[(size_t)b * N_ + n0 + t];
    __syncthreads();
    float b0 = bias[2 * t], b1 = bias[2 * t + 1];
    const float* Otb = Ot + (size_t)b * 512 * NC_;
    for (int g = 0; g < 4; ++g) {
        const unsigned int* wg = Wg + (size_t)(b * 4 + g) * NC_ * 256 + t;
        float wx[NC_], wy[NC_];
#pragma unroll
        for (int c = 0; c < NC_; ++c) {
            unsigned u = wg[c * 256];
            wx[c] = bfu2f((unsigned short)u);
            wy[c] = bfu2f((unsigned short)(u >> 16));
        }
        for (int i = 0; i < 64; ++i) {
            int r = r_lds[i];                    // block-uniform
            if ((r & 3) != g) continue;          // uniform branch
            int rq = r >> 2;
            const float4* op = (const float4*)(Otb + rq * NC_);
            float o[NC_];
            *(float4*)&o[0]  = op[0];
            *(float4*)&o[4]  = op[1];
            *(float4*)&o[8]  = op[2];
            *(float4*)&o[12] = op[3];
            float a0 = b0, a1 = b1;
#pragma unroll
            for (int c = 0; c < NC_; ++c) { a0 += o[c] * wx[c]; a1 += o[c] * wy[c]; }
            float2 res; res.x = a0; res.y = a1;
            *(float2*)(xout + ((size_t)b * N_ + n0 + i) * 512 + 2 * t) = res;
        }
    }
}

// ---------------- launch ----------------
extern "C" void kernel_launch(void* const* d_in, const int* in_sizes, int n_in,
                              void* d_out, int out_size, void* d_ws, size_t ws_size,
                              hipStream_t stream) {
    const float* x_token = (const float*)d_in[0];
    const int* idx_cluster = (const int*)d_in[2];
    const float* Wqk = (const float*)d_in[4];
    const float* Wv = (const float*)d_in[5];
    const float* Wproj = (const float*)d_in[7];
    const float* bproj = (const float*)d_in[8];

    float* x_out = (float*)d_out;                               // [8][2048][512]
    float* attn = x_out + (size_t)B_ * N_ * C_;                 // [8][2048][2048]

    char* ws = (char*)d_ws;
    size_t off = 0;
    auto alloc = [&](size_t bytes) {
        void* p = ws + off;
        off += (bytes + 255) & ~(size_t)255;
        return p;
    };
    unsigned short* WqkT = (unsigned short*)alloc(1024 * 512 * 2);
    unsigned short* xbf = (unsigned short*)alloc((size_t)B_ * N_ * C_ * 2);
    unsigned short* qbf = (unsigned short*)alloc((size_t)B_ * N_ * C_ * 2);
    unsigned short* kbf = (unsigned short*)alloc((size_t)B_ * N_ * C_ * 2);
    int* shuf = (int*)alloc((size_t)B_ * N_ * 4);
    int* restore = (int*)alloc((size_t)B_ * N_ * 4);
    int* svals = (int*)alloc((size_t)B_ * N_ * 4);
    int* dbl = (int*)alloc((size_t)B_ * N_ * 4);
    int* cstart = (int*)alloc(B_ * 17 * 4);
    float* Ot = (float*)alloc((size_t)B_ * 512 * NC_ * 4);
    float* xepart = (float*)alloc((size_t)B_ * SL_ * NC_ * 512 * 4);   // 2 MB
    float* Spart = (float*)alloc((size_t)B_ * SL_ * NC_ * 4);
    float* xe = (float*)alloc((size_t)B_ * NC_ * 512 * 4);
    float* Stot = (float*)alloc((size_t)B_ * NC_ * 4);
    unsigned int* Wg = (unsigned int*)alloc((size_t)B_ * 4 * NC_ * 256 * 4);  // bf16 pairs

    // 1. converts
    cvt_x<<<dim3((B_ * N_ * C_) / (256 * 4)), dim3(256), 0, stream>>>((const float4*)x_token, xbf);
    cvt_wqk<<<dim3((1024 * 512) / 256), dim3(256), 0, stream>>>(Wqk, WqkT);

    // 2. stable sort / index tables
    sort_kernel<<<dim3(B_), dim3(256), 0, stream>>>(idx_cluster, shuf, restore, svals, dbl, cstart);

    // 3. grouped projection weights (range-based from cstart)
    build_wg<<<dim3(NC_, B_ * 4), dim3(256), 0, stream>>>(Wproj, cstart, Wg);

    // 4. qk GEMM: [16384x512] @ [512x1024] (v eliminated)
    gemm_bt<0><<<dim3(1024 / 128, 16384 / 128, 1), dim3(256), 0, stream>>>(
        xbf, WqkT, nullptr, qbf, kbf);

    // 5. attn_map = q @ k^T * SCALE  (per batch) -> output chunk 1
    gemm_bt<1><<<dim3(N_ / 128, N_ / 128, B_), dim3(256), 0, stream>>>(
        qbf, kbf, attn, nullptr, nullptr);

    // 6. sliced softmax-collapse per (batch, cluster, slice) on x (not v)
    cluster_reduce2<<<dim3(NC_, B_, SL_), dim3(256), 0, stream>>>(
        attn, shuf, dbl, cstart, xbf, xepart, Spart);

    // 7. combine slices -> xe, Stot
    combine_xe<<<dim3(NC_, B_), dim3(256), 0, stream>>>(xepart, Spart, xe, Stot);

    // 8. O = (xe @ Wv) / S -> Ot[b][d][c]
    ovw_kernel<<<dim3(NC_, B_), dim3(256), 0, stream>>>(xe, Stot, Wv, Ot);

    // 9. x_out = gather-K16-GEMM + bias -> output chunk 0
    xout_kernel<<<dim3(N_ / 64, B_), dim3(256), 0, stream>>>(Ot, Wg, restore, bproj, x_out);
}

// Round 7
// 388.161 us; speedup vs baseline: 1.0049x; 1.0049x over previous
//
#include <hip/hip_runtime.h>
#include <hip/hip_bf16.h>

// ---------------- helpers ----------------
typedef __attribute__((ext_vector_type(8))) short short8;
typedef __attribute__((ext_vector_type(4))) float floatx4;

__device__ __forceinline__ unsigned short f2bfu(float f) {
    unsigned u = __float_as_uint(f);
    unsigned rounding = 0x7fffu + ((u >> 16) & 1u);
    return (unsigned short)((u + rounding) >> 16);
}
__device__ __forceinline__ float bfu2f(unsigned short u) {
    return __uint_as_float(((unsigned)u) << 16);
}

// async global->LDS, 16B per lane; LDS dest = wave-uniform base + lane*16
__device__ __forceinline__ void async_ld16(const void* g, void* l) {
    __builtin_amdgcn_global_load_lds(
        (const __attribute__((address_space(1))) void*)g,
        (__attribute__((address_space(3))) void*)l, 16, 0, 0);
}

#define B_  8
#define N_  2048
#define C_  512
#define NC_ 16   // clusters
#define SL_ 8    // cluster_reduce row slices

// ---------------- fused converts ----------------
// blocks [0, 8192): xbf = bf16(x_token), 4 floats/thread
// blocks [8192, 9216): Wq_bf[r][c] = bf16(Wqk[r][c]); Wk_bf[r][c] = bf16(Wqk[r][512+c])
__global__ __launch_bounds__(256) void cvt_all(const float4* __restrict__ x,
                                               const float* __restrict__ Wqk,
                                               unsigned short* __restrict__ xbf,
                                               unsigned short* __restrict__ Wq_bf,
                                               unsigned short* __restrict__ Wk_bf) {
    int bx = blockIdx.x, t = threadIdx.x;
    if (bx < 8192) {
        size_t i = (size_t)bx * 256 + t;
        float4 f = x[i];
        uint2 p;
        p.x = (unsigned)f2bfu(f.x) | ((unsigned)f2bfu(f.y) << 16);
        p.y = (unsigned)f2bfu(f.z) | ((unsigned)f2bfu(f.w) << 16);
        *(uint2*)(xbf + 4 * i) = p;
    } else {
        int id = (bx - 8192) * 256 + t;        // over 512*512
        int r = id >> 9, c = id & 511;
        Wq_bf[id] = f2bfu(Wqk[(size_t)r * 1024 + c]);
        Wk_bf[id] = f2bfu(Wqk[(size_t)r * 1024 + 512 + c]);
    }
}

// ---------------- stable counting sort per batch ----------------
__global__ __launch_bounds__(256) void sort_kernel(const int* __restrict__ idx_cluster,
                                                   int* __restrict__ shuf,
                                                   int* __restrict__ restore,
                                                   int* __restrict__ svals,
                                                   int* __restrict__ dbl,
                                                   int* __restrict__ cstart) {
    int b = blockIdx.x, t = threadIdx.x;
    __shared__ int vals[N_];
    __shared__ int seghist[256 * 17];   // stride 17 to spread banks
    __shared__ int cbase[NC_], ctot[NC_];
    __shared__ int shufs[N_];
    const int* src = idx_cluster + (size_t)b * N_;
    for (int j = t; j < N_; j += 256) vals[j] = src[j];
    for (int c = 0; c < NC_; ++c) seghist[t * 17 + c] = 0;
    __syncthreads();
    // count: thread t owns positions t*8 .. t*8+7 (contiguous -> stable)
    for (int i = 0; i < 8; ++i) {
        int c = vals[t * 8 + i];
        seghist[t * 17 + c]++;
    }
    __syncthreads();
    if (t < NC_) {   // exclusive scan over segments for cluster t
        int run = 0;
        for (int s = 0; s < 256; ++s) {
            int x = seghist[s * 17 + t];
            seghist[s * 17 + t] = run;
            run += x;
        }
        ctot[t] = run;
    }
    __syncthreads();
    if (t == 0) {
        int run = 0;
        for (int c = 0; c < NC_; ++c) {
            cbase[c] = run;
            cstart[b * 17 + c] = run;
            run += ctot[c];
        }
        cstart[b * 17 + NC_] = run;   // == N_
    }
    __syncthreads();
    for (int i = 0; i < 8; ++i) {
        int p = t * 8 + i;
        int c = vals[p];
        int pos = cbase[c] + seghist[t * 17 + c];
        seghist[t * 17 + c]++;
        shufs[pos] = p;
    }
    __syncthreads();
    for (int j = t; j < N_; j += 256) {
        int sj = shufs[j];
        shuf[(size_t)b * N_ + j] = sj;
        svals[(size_t)b * N_ + j] = vals[sj];
        restore[(size_t)b * N_ + sj] = j;
        dbl[(size_t)b * N_ + j] = shufs[sj];
    }
}

// ---------------- bf16 MFMA GEMM, A (MxK) row-major, Bt (NxK) row-major ----------------
// EXACT R0 core, no block remap (R5/R6 A/B: swizzle neutral; schedules frozen).
// Single-buffer 128x64 tiles (32 KiB LDS), 2 __syncthreads per K-step,
// global_load_lds width=16 staging, source-side XOR swizzle (chunk ^= row&7).
// MODE 0: bf16 output, row stride 512 (used for MT 512x512 and xM 16384x512)
// MODE 1: attn (per-batch 2048x2048) -> f32 * SCALE, plus fused e-extraction:
//   evals[b][j] = exp(attn[b, dbl[j], j]) written by the block/thread owning
//   that element (dbl staged in LDS; each j hit exactly once grid-wide).
template <int MODE>
__global__ __launch_bounds__(256) void gemm_bt(const unsigned short* __restrict__ A,
                                               const unsigned short* __restrict__ Bt,
                                               float* __restrict__ outF,
                                               unsigned short* __restrict__ outB,
                                               const int* __restrict__ dbl,
                                               float* __restrict__ evals) {
    constexpr int K = 512;
    int t = threadIdx.x;
    int lane = t & 63, wave = t >> 6;
    int wm = (wave & 1) * 64, wn = (wave >> 1) * 64;
    int m0 = blockIdx.y * 128, n0 = blockIdx.x * 128;
    size_t b = 0;
    if (MODE == 1) {
        b = blockIdx.z;
        A += b * (size_t)N_ * 512;
        Bt += b * (size_t)N_ * 512;
        outF += b * (size_t)N_ * N_;
    }
    __shared__ __align__(16) unsigned short As[128 * 64];
    __shared__ __align__(16) unsigned short Bs[128 * 64];
    __shared__ int dbl_lds[MODE == 1 ? 128 : 1];
    if (MODE == 1 && t < 128) dbl_lds[t] = dbl[b * N_ + n0 + t];
    floatx4 acc[4][4] = {};
    int l15 = lane & 15, q4 = lane >> 4;
    // staging: lane covers row (lane>>3) within its 8-row group, chunk (lane&7)
    int srow = lane >> 3, schk = lane & 7;
    int sgc = schk ^ srow;            // source chunk after XOR swizzle (row&7 == srow)
    int xr = l15 & 7;                 // fragment-read XOR (row&7 == l15&7 for all mi/ni)

    for (int k0 = 0; k0 < K; k0 += 64) {
        __syncthreads();   // previous-iter LDS reads done before overwrite
#pragma unroll
        for (int i = 0; i < 4; ++i) {
            int cid = i * 4 + wave;                 // 1KB group id (16 groups of 8 rows)
            int row = cid * 8 + srow;
            async_ld16(A + (size_t)(m0 + row) * 512 + k0 + sgc * 8, (char*)As + cid * 1024);
            async_ld16(Bt + (size_t)(n0 + row) * 512 + k0 + sgc * 8, (char*)Bs + cid * 1024);
        }
        __syncthreads();   // drains vmcnt (async LDS writes visible)
#pragma unroll
        for (int kk = 0; kk < 2; ++kk) {
            int csw = (((kk * 4 + q4) ^ xr) * 8);   // swizzled chunk offset (elements)
            short8 af[4], bfr[4];
#pragma unroll
            for (int mi = 0; mi < 4; ++mi)
                af[mi] = *(const short8*)(&As[(wm + mi * 16 + l15) * 64 + csw]);
#pragma unroll
            for (int ni = 0; ni < 4; ++ni)
                bfr[ni] = *(const short8*)(&Bs[(wn + ni * 16 + l15) * 64 + csw]);
#pragma unroll
            for (int mi = 0; mi < 4; ++mi)
#pragma unroll
                for (int ni = 0; ni < 4; ++ni)
                    acc[mi][ni] = __builtin_amdgcn_mfma_f32_16x16x32_bf16(af[mi], bfr[ni], acc[mi][ni], 0, 0, 0);
        }
    }
    // epilogue: D[row=q4*4+r][col=l15] per 16x16 tile
#pragma unroll
    for (int mi = 0; mi < 4; ++mi) {
#pragma unroll
        for (int ni = 0; ni < 4; ++ni) {
            int colL = wn + ni * 16 + l15;
            int dj = (MODE == 1) ? dbl_lds[colL] : 0;
#pragma unroll
            for (int r = 0; r < 4; ++r) {
                int rowL = wm + mi * 16 + q4 * 4 + r;
                float v = acc[mi][ni][r];
                if (MODE == 0) {
                    outB[(size_t)(m0 + rowL) * 512 + n0 + colL] = f2bfu(v);
                } else {
                    float av = v * 0.125f;
                    outF[(size_t)(m0 + rowL) * N_ + n0 + colL] = av;
                    if (dj == m0 + rowL)
                        evals[b * N_ + n0 + colL] = expf(av);
                }
            }
        }
    }
}

// ---------------- sliced per-(batch,cluster) softmax-collapse reduction ----------------
// e from evals (precomputed in attn epilogue, coalesced read).
// v eliminated: xepart[b][sl][c][d] = sum_{i in slice} e_i * x_bf[b,shuf[i],d]
// Spart[b][sl][c] = sum_{i in slice} e_i
__global__ __launch_bounds__(256) void cluster_reduce2(const float* __restrict__ evals,
                                                       const int* __restrict__ shuf,
                                                       const int* __restrict__ cstart,
                                                       const unsigned short* __restrict__ xbf,
                                                       float* __restrict__ xepart,
                                                       float* __restrict__ Spart) {
    int c = blockIdx.x, b = blockIdx.y, sl = blockIdx.z, t = threadIdx.x;
    int start = cstart[b * 17 + c], end = cstart[b * 17 + c + 1];
    int n = end - start;
    int i0 = (n * sl) / SL_, i1 = (n * (sl + 1)) / SL_;
    int cnt = i1 - i0;                 // <= ceil(2048/8) = 256
    __shared__ float e_lds[256];
    __shared__ int row_lds[256];
    if (t < cnt) {
        int j = start + i0 + t;
        e_lds[t] = evals[(size_t)b * N_ + j];
        row_lds[t] = shuf[(size_t)b * N_ + j];
    }
    __syncthreads();
    if (t == 0) {
        float s = 0.f;
        for (int i = 0; i < cnt; ++i) s += e_lds[i];
        Spart[(b * SL_ + sl) * NC_ + c] = s;
    }
    float a0 = 0.f, a1 = 0.f;
    for (int i = 0; i < cnt; ++i) {
        float e = e_lds[i];
        unsigned u = *(const unsigned*)(xbf + ((size_t)b * N_ + row_lds[i]) * 512 + 2 * t);
        a0 += e * bfu2f((unsigned short)u);
        a1 += e * bfu2f((unsigned short)(u >> 16));
    }
    float2 o; o.x = a0; o.y = a1;
    *(float2*)(xepart + (((size_t)(b * SL_ + sl) * NC_ + c) * 512 + 2 * t)) = o;
}

// ---------------- combine slices + O = (xe @ Wv) / S -> Ot[b][d][c] ----------------
__global__ __launch_bounds__(256) void ovw_kernel(const float* __restrict__ xepart,
                                                  const float* __restrict__ Spart,
                                                  const float* __restrict__ Wv,
                                                  float* __restrict__ Ot) {
    int c = blockIdx.x, b = blockIdx.y, t = threadIdx.x;
    __shared__ float xl[512];
    for (int i = t; i < 512; i += 256) {
        float s = 0.f;
#pragma unroll
        for (int sl = 0; sl < SL_; ++sl)
            s += xepart[(((size_t)(b * SL_ + sl) * NC_ + c) * 512 + i)];
        xl[i] = s;
    }
    __syncthreads();
    float S = 0.f;
#pragma unroll
    for (int sl = 0; sl < SL_; ++sl) S += Spart[(b * SL_ + sl) * NC_ + c];
    float inv = S > 0.f ? 1.f / S : 0.f;
    float a0 = 0.f, a1 = 0.f;
    for (int k = 0; k < 512; ++k) {
        float xv = xl[k];                                  // LDS broadcast
        float2 w = *(const float2*)(Wv + (size_t)k * 512 + 2 * t);
        a0 += xv * w.x; a1 += xv * w.y;
    }
    Ot[((size_t)b * 512 + 2 * t) * NC_ + c] = a0 * inv;
    Ot[((size_t)b * 512 + 2 * t + 1) * NC_ + c] = a1 * inv;
}

// ---------------- grouped projection weights (parallel, range-based) ----------------
__global__ __launch_bounds__(256) void build_wg(const float* __restrict__ Wproj,
                                                const int* __restrict__ cstart,
                                                unsigned int* __restrict__ Wg) {
    int c = blockIdx.x;          // cluster
    int bg = blockIdx.y;         // b*4+g
    int b = bg >> 2, g = bg & 3;
    int t = threadIdx.x;
    int lo = cstart[b * 17 + c] - g * 512;
    int hi = cstart[b * 17 + c + 1] - g * 512;
    lo = lo < 0 ? 0 : lo;
    hi = hi > 512 ? 512 : hi;
    float a0 = 0.f, a1 = 0.f;
    for (int cd = lo; cd < hi; ++cd) {
        float2 w = *(const float2*)(Wproj + (size_t)cd * 512 + 2 * t);
        a0 += w.x; a1 += w.y;
    }
    Wg[(size_t)bg * NC_ * 256 + c * 256 + t] =
        (unsigned)f2bfu(a0) | ((unsigned)f2bfu(a1) << 16);   // empty range -> 0
}

// ---------------- final projection: x_out[b,n,m] = sum_c Ot[b,rq,c]*Wg[b,g,c,m] + bias[m] ----
__global__ __launch_bounds__(256) void xout_kernel(const float* __restrict__ Ot,
                                                   const unsigned int* __restrict__ Wg,
                                                   const int* __restrict__ restore,
                                                   const float* __restrict__ bias,
                                                   float* __restrict__ xout) {
    int nb = blockIdx.x, b = blockIdx.y, t = threadIdx.x;
    int n0 = nb * 64;
    __shared__ int r_lds[64];
    if (t < 64) r_lds[t] = restore[(size_t)b * N_ + n0 + t];
    __syncthreads();
    float b0 = bias[2 * t], b1 = bias[2 * t + 1];
    const float* Otb = Ot + (size_t)b * 512 * NC_;
    for (int g = 0; g < 4; ++g) {
        const unsigned int* wg = Wg + (size_t)(b * 4 + g) * NC_ * 256 + t;
        float wx[NC_], wy[NC_];
#pragma unroll
        for (int c = 0; c < NC_; ++c) {
            unsigned u = wg[c * 256];
            wx[c] = bfu2f((unsigned short)u);
            wy[c] = bfu2f((unsigned short)(u >> 16));
        }
        for (int i = 0; i < 64; ++i) {
            int r = r_lds[i];                    // block-uniform
            if ((r & 3) != g) continue;          // uniform branch
            int rq = r >> 2;
            const float4* op = (const float4*)(Otb + rq * NC_);
            float o[NC_];
            *(float4*)&o[0]  = op[0];
            *(float4*)&o[4]  = op[1];
            *(float4*)&o[8]  = op[2];
            *(float4*)&o[12] = op[3];
            float a0 = b0, a1 = b1;
#pragma unroll
            for (int c = 0; c < NC_; ++c) { a0 += o[c] * wx[c]; a1 += o[c] * wy[c]; }
            float2 res; res.x = a0; res.y = a1;
            *(float2*)(xout + ((size_t)b * N_ + n0 + i) * 512 + 2 * t) = res;
        }
    }
}

// ---------------- launch ----------------
extern "C" void kernel_launch(void* const* d_in, const int* in_sizes, int n_in,
                              void* d_out, int out_size, void* d_ws, size_t ws_size,
                              hipStream_t stream) {
    const float* x_token = (const float*)d_in[0];
    const int* idx_cluster = (const int*)d_in[2];
    const float* Wqk = (const float*)d_in[4];
    const float* Wv = (const float*)d_in[5];
    const float* Wproj = (const float*)d_in[7];
    const float* bproj = (const float*)d_in[8];

    float* x_out = (float*)d_out;                               // [8][2048][512]
    float* attn = x_out + (size_t)B_ * N_ * C_;                 // [8][2048][2048]

    char* ws = (char*)d_ws;
    size_t off = 0;
    auto alloc = [&](size_t bytes) {
        void* p = ws + off;
        off += (bytes + 255) & ~(size_t)255;
        return p;
    };
    unsigned short* Wq_bf = (unsigned short*)alloc(512 * 512 * 2);
    unsigned short* Wk_bf = (unsigned short*)alloc(512 * 512 * 2);
    unsigned short* MT_bf = (unsigned short*)alloc(512 * 512 * 2);
    unsigned short* xbf = (unsigned short*)alloc((size_t)B_ * N_ * C_ * 2);
    unsigned short* xMbf = (unsigned short*)alloc((size_t)B_ * N_ * C_ * 2);
    int* shuf = (int*)alloc((size_t)B_ * N_ * 4);
    int* restore = (int*)alloc((size_t)B_ * N_ * 4);
    int* svals = (int*)alloc((size_t)B_ * N_ * 4);
    int* dbl = (int*)alloc((size_t)B_ * N_ * 4);
    int* cstart = (int*)alloc(B_ * 17 * 4);
    float* evals = (float*)alloc((size_t)B_ * N_ * 4);
    float* Ot = (float*)alloc((size_t)B_ * 512 * NC_ * 4);
    float* xepart = (float*)alloc((size_t)B_ * SL_ * NC_ * 512 * 4);   // 2 MB
    float* Spart = (float*)alloc((size_t)B_ * SL_ * NC_ * 4);
    unsigned int* Wg = (unsigned int*)alloc((size_t)B_ * 4 * NC_ * 256 * 4);  // bf16 pairs

    // 1. fused converts: xbf + Wq_bf/Wk_bf
    cvt_all<<<dim3(8192 + 1024), dim3(256), 0, stream>>>(
        (const float4*)x_token, Wqk, xbf, Wq_bf, Wk_bf);

    // 2. stable sort / index tables
    sort_kernel<<<dim3(B_), dim3(256), 0, stream>>>(idx_cluster, shuf, restore, svals, dbl, cstart);

    // 3. grouped projection weights (range-based from cstart)
    build_wg<<<dim3(NC_, B_ * 4), dim3(256), 0, stream>>>(Wproj, cstart, Wg);

    // 4. MT[e][c] = sum_d Wk_bf[e][d]*Wq_bf[c][d]  (= (Wq Wk^T)[c][e], 512x512)
    gemm_bt<0><<<dim3(512 / 128, 512 / 128, 1), dim3(256), 0, stream>>>(
        Wk_bf, Wq_bf, nullptr, MT_bf, nullptr, nullptr);

    // 5. xM = x @ M : [16384x512] @ (MT as Bt)  -> bf16
    gemm_bt<0><<<dim3(512 / 128, 16384 / 128, 1), dim3(256), 0, stream>>>(
        xbf, MT_bf, nullptr, xMbf, nullptr, nullptr);

    // 6. attn = xM @ x^T * SCALE (per batch) -> output chunk 1, + fused evals
    gemm_bt<1><<<dim3(N_ / 128, N_ / 128, B_), dim3(256), 0, stream>>>(
        xMbf, xbf, attn, nullptr, dbl, evals);

    // 7. sliced softmax-collapse per (batch, cluster, slice) on x
    cluster_reduce2<<<dim3(NC_, B_, SL_), dim3(256), 0, stream>>>(
        evals, shuf, cstart, xbf, xepart, Spart);

    // 8. combine + O = (xe @ Wv)/S -> Ot[b][d][c]
    ovw_kernel<<<dim3(NC_, B_), dim3(256), 0, stream>>>(xepart, Spart, Wv, Ot);

    // 9. x_out = gather-K16-GEMM + bias -> output chunk 0
    xout_kernel<<<dim3(N_ / 64, B_), dim3(256), 0, stream>>>(Ot, Wg, restore, bproj, x_out);
}

// Round 8
// 355.817 us; speedup vs baseline: 1.0963x; 1.0909x over previous
//
#include <hip/hip_runtime.h>
#include <hip/hip_bf16.h>

// ---------------- helpers ----------------
typedef __attribute__((ext_vector_type(8))) short short8;
typedef __attribute__((ext_vector_type(4))) float floatx4;

__device__ __forceinline__ unsigned short f2bfu(float f) {
    unsigned u = __float_as_uint(f);
    unsigned rounding = 0x7fffu + ((u >> 16) & 1u);
    return (unsigned short)((u + rounding) >> 16);
}
__device__ __forceinline__ float bfu2f(unsigned short u) {
    return __uint_as_float(((unsigned)u) << 16);
}

// async global->LDS, 16B per lane; LDS dest = wave-uniform base + lane*16
__device__ __forceinline__ void async_ld16(const void* g, void* l) {
    __builtin_amdgcn_global_load_lds(
        (const __attribute__((address_space(1))) void*)g,
        (__attribute__((address_space(3))) void*)l, 16, 0, 0);
}

#define B_  8
#define N_  2048
#define C_  512
#define NC_ 16   // clusters

// ---------------- convert kernels (R0-identical where present) ----------------
__global__ __launch_bounds__(256) void cvt_x(const float4* __restrict__ x,
                                             unsigned short* __restrict__ xbf) {
    size_t i = (size_t)blockIdx.x * 256 + threadIdx.x;   // 4 floats per thread
    float4 f = x[i];
    unsigned short u0 = f2bfu(f.x), u1 = f2bfu(f.y), u2 = f2bfu(f.z), u3 = f2bfu(f.w);
    uint2 p;
    p.x = (unsigned)u0 | ((unsigned)u1 << 16);
    p.y = (unsigned)u2 | ((unsigned)u3 << 16);
    *(uint2*)(xbf + 4 * i) = p;
}

// WqkT[n][k], n in [0,1024), k in [0,512): = Wqk[k][n]  (v eliminated algebraically)
__global__ __launch_bounds__(256) void cvt_wqk(const float* __restrict__ Wqk,
                                               unsigned short* __restrict__ WT) {
    int id = blockIdx.x * 256 + threadIdx.x;   // 1024*512 total
    int n = id >> 9, k = id & 511;
    WT[id] = f2bfu(Wqk[(size_t)k * 1024 + n]);
}

__global__ __launch_bounds__(256) void cvt_wproj(const float* __restrict__ W,
                                                 unsigned short* __restrict__ WT) {
    int id = blockIdx.x * 256 + threadIdx.x;   // 512*512 total
    int n = id >> 9, k = id & 511;
    WT[id] = f2bfu(W[(size_t)k * 512 + n]);
}

// ---------------- stable counting sort per batch (R0-identical) ----------------
__global__ __launch_bounds__(256) void sort_kernel(const int* __restrict__ idx_cluster,
                                                   int* __restrict__ shuf,
                                                   int* __restrict__ restore,
                                                   int* __restrict__ svals,
                                                   int* __restrict__ dbl,
                                                   int* __restrict__ cstart) {
    int b = blockIdx.x, t = threadIdx.x;
    __shared__ int vals[N_];
    __shared__ int seghist[256 * 17];   // stride 17 to spread banks
    __shared__ int cbase[NC_], ctot[NC_];
    __shared__ int shufs[N_];
    const int* src = idx_cluster + (size_t)b * N_;
    for (int j = t; j < N_; j += 256) vals[j] = src[j];
    for (int c = 0; c < NC_; ++c) seghist[t * 17 + c] = 0;
    __syncthreads();
    // count: thread t owns positions t*8 .. t*8+7 (contiguous -> stable)
    for (int i = 0; i < 8; ++i) {
        int c = vals[t * 8 + i];
        seghist[t * 17 + c]++;
    }
    __syncthreads();
    if (t < NC_) {   // exclusive scan over segments for cluster t
        int run = 0;
        for (int s = 0; s < 256; ++s) {
            int x = seghist[s * 17 + t];
            seghist[s * 17 + t] = run;
            run += x;
        }
        ctot[t] = run;
    }
    __syncthreads();
    if (t == 0) {
        int run = 0;
        for (int c = 0; c < NC_; ++c) {
            cbase[c] = run;
            cstart[b * 17 + c] = run;
            run += ctot[c];
        }
        cstart[b * 17 + NC_] = run;   // == N_
    }
    __syncthreads();
    for (int i = 0; i < 8; ++i) {
        int p = t * 8 + i;
        int c = vals[p];
        int pos = cbase[c] + seghist[t * 17 + c];
        seghist[t * 17 + c]++;
        shufs[pos] = p;
    }
    __syncthreads();
    for (int j = t; j < N_; j += 256) {
        int sj = shufs[j];
        shuf[(size_t)b * N_ + j] = sj;
        svals[(size_t)b * N_ + j] = vals[sj];
        restore[(size_t)b * N_ + sj] = j;
        dbl[(size_t)b * N_ + j] = shufs[sj];
    }
}

// ---------------- bf16 MFMA GEMM (EXACT R0 core & schedule) ----------------
// m97 pattern: global_load_lds width=16 staging, unpadded 128x64 LDS tiles,
// source-side XOR swizzle (chunk ^= row&7) to kill ds_read_b128 bank conflicts.
// MODE 0: qk   (N=1024) -> split bf16 q/k
// MODE 1: attn (per-batch 2048x2048) -> f32 * SCALE
// MODE 2: proj (N=512) -> f32 + bias
template <int MODE>
__global__ __launch_bounds__(256) void gemm_bt(const unsigned short* __restrict__ A,
                                               const unsigned short* __restrict__ Bt,
                                               float* __restrict__ outF,
                                               unsigned short* __restrict__ outQ,
                                               unsigned short* __restrict__ outK,
                                               const float* __restrict__ bias) {
    constexpr int K = 512;
    int t = threadIdx.x;
    int lane = t & 63, wave = t >> 6;
    int wm = (wave & 1) * 64, wn = (wave >> 1) * 64;
    int m0 = blockIdx.y * 128, n0 = blockIdx.x * 128;
    if (MODE == 1) {
        size_t b = blockIdx.z;
        A += b * (size_t)N_ * 512;
        Bt += b * (size_t)N_ * 512;
        outF += b * (size_t)N_ * N_;
    }
    __shared__ __align__(16) unsigned short As[128 * 64];
    __shared__ __align__(16) unsigned short Bs[128 * 64];
    floatx4 acc[4][4] = {};
    int l15 = lane & 15, q4 = lane >> 4;
    // staging: lane covers row (lane>>3) within its 8-row group, chunk (lane&7)
    int srow = lane >> 3, schk = lane & 7;
    int sgc = schk ^ srow;            // source chunk after XOR swizzle (row&7 == srow)
    int xr = l15 & 7;                 // fragment-read XOR (row&7 == l15&7 for all mi/ni)

    for (int k0 = 0; k0 < K; k0 += 64) {
        __syncthreads();   // previous-iter LDS reads done before overwrite
#pragma unroll
        for (int i = 0; i < 4; ++i) {
            int cid = i * 4 + wave;                 // 1KB group id (16 groups of 8 rows)
            int row = cid * 8 + srow;
            async_ld16(A + (size_t)(m0 + row) * 512 + k0 + sgc * 8, (char*)As + cid * 1024);
            async_ld16(Bt + (size_t)(n0 + row) * 512 + k0 + sgc * 8, (char*)Bs + cid * 1024);
        }
        __syncthreads();   // drains vmcnt (async LDS writes visible)
#pragma unroll
        for (int kk = 0; kk < 2; ++kk) {
            int csw = (((kk * 4 + q4) ^ xr) * 8);   // swizzled chunk offset (elements)
            short8 af[4], bfr[4];
#pragma unroll
            for (int mi = 0; mi < 4; ++mi)
                af[mi] = *(const short8*)(&As[(wm + mi * 16 + l15) * 64 + csw]);
#pragma unroll
            for (int ni = 0; ni < 4; ++ni)
                bfr[ni] = *(const short8*)(&Bs[(wn + ni * 16 + l15) * 64 + csw]);
#pragma unroll
            for (int mi = 0; mi < 4; ++mi)
#pragma unroll
                for (int ni = 0; ni < 4; ++ni)
                    acc[mi][ni] = __builtin_amdgcn_mfma_f32_16x16x32_bf16(af[mi], bfr[ni], acc[mi][ni], 0, 0, 0);
        }
    }
    // epilogue: D[row=q4*4+r][col=l15] per 16x16 tile
#pragma unroll
    for (int mi = 0; mi < 4; ++mi) {
#pragma unroll
        for (int ni = 0; ni < 4; ++ni) {
#pragma unroll
            for (int r = 0; r < 4; ++r) {
                int row = m0 + wm + mi * 16 + q4 * 4 + r;
                int col = n0 + wn + ni * 16 + l15;
                float v = acc[mi][ni][r];
                if (MODE == 0) {
                    unsigned short u = f2bfu(v);
                    if (col < 512) outQ[(size_t)row * 512 + col] = u;
                    else           outK[(size_t)row * 512 + col - 512] = u;
                } else if (MODE == 1) {
                    outF[(size_t)row * N_ + col] = v * 0.125f;
                } else {
                    outF[(size_t)row * 512 + col] = v + bias[col];
                }
            }
        }
    }
}

// ---------------- per-(batch,cluster) softmax-collapse reduction (R0 structure) ----------------
// e_j = exp(attn[b, dbl[j], j]); v eliminated: accumulate x instead of v.
// xe[b][c][d] = (sum_j e_j * x_bf[b,shuf[j],d]) / (sum_j e_j)   (normalized here)
__global__ __launch_bounds__(256) void cluster_reduce(const float* __restrict__ attn,
                                                      const int* __restrict__ shuf,
                                                      const int* __restrict__ dbl,
                                                      const int* __restrict__ cstart,
                                                      const unsigned short* __restrict__ xbf,
                                                      float* __restrict__ xe) {
    int c = blockIdx.x, b = blockIdx.y, t = threadIdx.x;
    int start = cstart[b * 17 + c], end = cstart[b * 17 + c + 1];
    int n = end - start;
    if (n <= 0) return;   // xe[b][c][*] stale; Ot[b][*][c] never read for empty cluster
    __shared__ float e_lds[N_];
    __shared__ float Sred;
    if (t == 0) Sred = 0.f;
    __syncthreads();
    float ps = 0.f;
    for (int i = t; i < n; i += 256) {
        int j = start + i;
        int dj = dbl[(size_t)b * N_ + j];
        float cv = attn[(size_t)b * N_ * N_ + (size_t)dj * N_ + j];
        float e = expf(cv);
        e_lds[i] = e;
        ps += e;
    }
    atomicAdd(&Sred, ps);
    __syncthreads();
    float t0 = 0.f, t1 = 0.f;
    for (int i = 0; i < n; ++i) {
        float e = e_lds[i];
        int row = shuf[(size_t)b * N_ + start + i];
        unsigned u = *(const unsigned*)(xbf + ((size_t)b * N_ + row) * 512 + 2 * t);
        t0 += e * bfu2f((unsigned short)u);
        t1 += e * bfu2f((unsigned short)(u >> 16));
    }
    float inv = 1.f / Sred;
    float2 r; r.x = t0 * inv; r.y = t1 * inv;
    *(float2*)(xe + ((size_t)b * NC_ + c) * 512 + 2 * t) = r;
}

// ---------------- Ot[b][d][c] = sum_k xe[b][c][k] * Wv[k][d]  (f32 Wv) ----------------
__global__ __launch_bounds__(256) void ovw_kernel(const float* __restrict__ xe,
                                                  const float* __restrict__ Wv,
                                                  float* __restrict__ Ot) {
    int c = blockIdx.x, b = blockIdx.y, t = threadIdx.x;
    __shared__ float xl[512];
    for (int i = t; i < 512; i += 256) xl[i] = xe[((size_t)b * NC_ + c) * 512 + i];
    __syncthreads();
    float a0 = 0.f, a1 = 0.f;
    for (int k = 0; k < 512; ++k) {
        float xv = xl[k];                                  // LDS broadcast
        float2 w = *(const float2*)(Wv + (size_t)k * 512 + 2 * t);
        a0 += xv * w.x; a1 += xv * w.y;
    }
    Ot[((size_t)b * 512 + 2 * t) * 16 + c] = a0;
    Ot[((size_t)b * 512 + 2 * t + 1) * 16 + c] = a1;
}

// ---------------- build out3 (bf16) = transpose-reshape-gather of O (R0-identical) ----------------
// out3[b,n,cd] = O[b, s[b,(r&3)*512+cd], r>>2],  r = restore[b,n]
__global__ __launch_bounds__(256) void build_out3(const float* __restrict__ Ot,
                                                  const int* __restrict__ svals,
                                                  const int* __restrict__ restore,
                                                  unsigned int* __restrict__ out3u) {
    int rg = blockIdx.x, b = blockIdx.y, t = threadIdx.x;
    __shared__ float Olds[512 * 16];
    __shared__ int slds[N_];
    for (int i = t; i < 512 * 16; i += 256) Olds[i] = Ot[(size_t)b * 512 * 16 + i];
    for (int i = t; i < N_; i += 256) slds[i] = svals[(size_t)b * N_ + i];
    __syncthreads();
    for (int n = rg * 64; n < rg * 64 + 64; ++n) {
        int r = restore[(size_t)b * N_ + n];
        int rq = r >> 2;
        int bj = (r & 3) * 512;
        int c0 = slds[bj + 2 * t];
        int c1 = slds[bj + 2 * t + 1];
        float v0 = Olds[rq * 16 + c0];
        float v1 = Olds[rq * 16 + c1];
        unsigned p = (unsigned)f2bfu(v0) | ((unsigned)f2bfu(v1) << 16);
        out3u[((size_t)b * N_ + n) * 256 + t] = p;
    }
}

// ---------------- launch ----------------
extern "C" void kernel_launch(void* const* d_in, const int* in_sizes, int n_in,
                              void* d_out, int out_size, void* d_ws, size_t ws_size,
                              hipStream_t stream) {
    const float* x_token = (const float*)d_in[0];
    const int* idx_cluster = (const int*)d_in[2];
    const float* Wqk = (const float*)d_in[4];
    const float* Wv = (const float*)d_in[5];
    const float* Wproj = (const float*)d_in[7];
    const float* bproj = (const float*)d_in[8];

    float* x_out = (float*)d_out;                               // [8][2048][512]
    float* attn = x_out + (size_t)B_ * N_ * C_;                 // [8][2048][2048]

    char* ws = (char*)d_ws;
    size_t off = 0;
    auto alloc = [&](size_t bytes) {
        void* p = ws + off;
        off += (bytes + 255) & ~(size_t)255;
        return p;
    };
    unsigned short* WqkT = (unsigned short*)alloc(1024 * 512 * 2);
    unsigned short* WprojT = (unsigned short*)alloc(512 * 512 * 2);
    unsigned short* xbf = (unsigned short*)alloc((size_t)B_ * N_ * C_ * 2);   // reused as out3
    unsigned short* qbf = (unsigned short*)alloc((size_t)B_ * N_ * C_ * 2);
    unsigned short* kbf = (unsigned short*)alloc((size_t)B_ * N_ * C_ * 2);
    int* shuf = (int*)alloc((size_t)B_ * N_ * 4);
    int* restore = (int*)alloc((size_t)B_ * N_ * 4);
    int* svals = (int*)alloc((size_t)B_ * N_ * 4);
    int* dbl = (int*)alloc((size_t)B_ * N_ * 4);
    int* cstart = (int*)alloc(B_ * 17 * 4);
    float* xe = (float*)alloc((size_t)B_ * NC_ * 512 * 4);
    float* Ot = (float*)alloc((size_t)B_ * 512 * 16 * 4);

    // 1. converts
    cvt_x<<<dim3((B_ * N_ * C_) / (256 * 4)), dim3(256), 0, stream>>>((const float4*)x_token, xbf);
    cvt_wqk<<<dim3((1024 * 512) / 256), dim3(256), 0, stream>>>(Wqk, WqkT);
    cvt_wproj<<<dim3((512 * 512) / 256), dim3(256), 0, stream>>>(Wproj, WprojT);

    // 2. stable sort / index tables
    sort_kernel<<<dim3(B_), dim3(256), 0, stream>>>(idx_cluster, shuf, restore, svals, dbl, cstart);

    // 3. qk GEMM: [16384x512] @ [512x1024] (v eliminated)
    gemm_bt<0><<<dim3(1024 / 128, 16384 / 128, 1), dim3(256), 0, stream>>>(
        xbf, WqkT, nullptr, qbf, kbf, nullptr);

    // 4. attn_map = q @ k^T * SCALE  (per batch) -> output chunk 1
    gemm_bt<1><<<dim3(N_ / 128, N_ / 128, B_), dim3(256), 0, stream>>>(
        qbf, kbf, attn, nullptr, nullptr, nullptr);

    // 5. softmax-collapse per (batch, cluster) on x -> normalized xe[b][c][d]
    cluster_reduce<<<dim3(NC_, B_), dim3(256), 0, stream>>>(attn, shuf, dbl, cstart, xbf, xe);

    // 6. Ot[b][d][c] = xe @ Wv
    ovw_kernel<<<dim3(NC_, B_), dim3(256), 0, stream>>>(xe, Wv, Ot);

    // 7. gather into out3 (bf16, aliases xbf)
    build_out3<<<dim3(N_ / 64, B_), dim3(256), 0, stream>>>(Ot, svals, restore, (unsigned int*)xbf);

    // 8. x_out = out3 @ Wproj + bproj -> output chunk 0
    gemm_bt<2><<<dim3(512 / 128, 16384 / 128, 1), dim3(256), 0, stream>>>(
        xbf, WprojT, x_out, nullptr, nullptr, bproj);
}